// Round 10
// baseline (243.768 us; speedup 1.0000x reference)
//
#include <hip/hip_runtime.h>
#include <hip/hip_fp16.h>
#include <math.h>

#define BATCH 4
#define SPATIAL (64*64*64)   // D*H*W = 262144
#define NB 512               // partial-reduction chunks per batch

typedef float f32x4 __attribute__((ext_vector_type(4)));
typedef unsigned int u32x4 __attribute__((ext_vector_type(4)));
typedef _Float16 f16x2 __attribute__((ext_vector_type(2)));

__device__ __forceinline__ float sigmoidf_(float z) { return 1.f / (1.f + expf(-z)); }

// f32 += dot(h2, w2) — v_dot2_f32_f16 when available
__device__ __forceinline__ float dot2acc(__half2 a, __half2 b, float c) {
#if __has_builtin(__builtin_amdgcn_fdot2)
  union { __half2 h; f16x2 f; } ua, ub;
  ua.h = a; ub.h = b;
  return __builtin_amdgcn_fdot2(ua.f, ub.f, c, false);
#else
  float2 fa = __half22float2(a), fb = __half22float2(b);
  return fmaf(fa.x, fb.x, fmaf(fa.y, fb.y, c));
#endif
}

// ---------------- Kernel A: partial spatial sum/max per (b, chunk, c); optional fp16 x copy ----------------
// psum/pmax layout: [b][c][chunk] (transposed for contiguous ca_kernel reads)
// 32 B/thread/iter: lane handles 2 consecutive voxel-groups (q covers voxels 2q, 2q+1)
template<bool W16>
__global__ __launch_bounds__(256) void pool_partial_kernel(
    const float* __restrict__ x, __half* __restrict__ x16,
    float* __restrict__ psum, float* __restrict__ pmax) {
  const int b     = blockIdx.x / NB;
  const int chunk = blockIdx.x % NB;
  const int tid  = threadIdx.x;
  const int w    = tid >> 6;
  const int lane = tid & 63;
  const int q    = lane >> 4;         // position-pair index (0..3)
  const int g    = lane & 15;         // channel group (4 ch each)

  const f32x4* xb = (const f32x4*)x + (size_t)b * SPATIAL * 16;
  uint2* x16b = (uint2*)x16 + (size_t)b * SPATIAL * 16;

  float s0=0.f, s1=0.f, s2=0.f, s3=0.f;
  float m0=-INFINITY, m1=-INFINITY, m2=-INFINITY, m3=-INFINITY;

  const int PPB = SPATIAL / NB;       // 512 positions per block
  #pragma unroll 4
  for (int i = 0; i < PPB / 32; ++i) {   // 16 iters; block covers 32 voxels/iter
    int p0 = chunk * PPB + i * 32 + w * 8 + q * 2;
    size_t gi0 = (size_t)p0 * 16 + g;
    size_t gi1 = gi0 + 16;
    f32x4 v0, v1;
    if (W16) {
      v0 = __builtin_nontemporal_load(xb + gi0);   // don't pollute L3 with fp32 x
      v1 = __builtin_nontemporal_load(xb + gi1);
    } else {
      v0 = xb[gi0]; v1 = xb[gi1];
    }
    if (W16) {
      union { __half2 h[2]; uint2 u; } pk0, pk1;
      pk0.h[0] = __floats2half2_rn(v0.x, v0.y);
      pk0.h[1] = __floats2half2_rn(v0.z, v0.w);
      pk1.h[0] = __floats2half2_rn(v1.x, v1.y);
      pk1.h[1] = __floats2half2_rn(v1.z, v1.w);
      x16b[gi0] = pk0.u;                           // normal store: want L3 residency
      x16b[gi1] = pk1.u;
    }
    s0 += v0.x + v1.x; s1 += v0.y + v1.y;
    s2 += v0.z + v1.z; s3 += v0.w + v1.w;
    m0 = fmaxf(m0, fmaxf(v0.x, v1.x)); m1 = fmaxf(m1, fmaxf(v0.y, v1.y));
    m2 = fmaxf(m2, fmaxf(v0.z, v1.z)); m3 = fmaxf(m3, fmaxf(v0.w, v1.w));
  }
  #pragma unroll
  for (int mask = 16; mask <= 32; mask <<= 1) {
    s0 += __shfl_xor(s0, mask); s1 += __shfl_xor(s1, mask);
    s2 += __shfl_xor(s2, mask); s3 += __shfl_xor(s3, mask);
    m0 = fmaxf(m0, __shfl_xor(m0, mask)); m1 = fmaxf(m1, __shfl_xor(m1, mask));
    m2 = fmaxf(m2, __shfl_xor(m2, mask)); m3 = fmaxf(m3, __shfl_xor(m3, mask));
  }
  __shared__ float lsum[4][64];
  __shared__ float lmax[4][64];
  if (q == 0) {
    lsum[w][g*4+0] = s0; lsum[w][g*4+1] = s1; lsum[w][g*4+2] = s2; lsum[w][g*4+3] = s3;
    lmax[w][g*4+0] = m0; lmax[w][g*4+1] = m1; lmax[w][g*4+2] = m2; lmax[w][g*4+3] = m3;
  }
  __syncthreads();
  if (tid < 64) {
    float s = lsum[0][tid] + lsum[1][tid] + lsum[2][tid] + lsum[3][tid];
    float m = fmaxf(fmaxf(lmax[0][tid], lmax[1][tid]), fmaxf(lmax[2][tid], lmax[3][tid]));
    psum[((size_t)b * 64 + tid) * NB + chunk] = s;   // transposed
    pmax[((size_t)b * 64 + tid) * NB + chunk] = m;
  }
}

// ---------------- Kernel B: finalize pools + MLP -> ca[B][C]; also emit half2 conv weights ----------------
__global__ __launch_bounds__(256) void ca_kernel(
    const float* __restrict__ psum, const float* __restrict__ pmax,
    const float* __restrict__ w1, const float* __restrict__ b1,
    const float* __restrict__ w2, const float* __restrict__ b2,
    const float* __restrict__ cw, __half2* __restrict__ w16,
    float* __restrict__ ca) {
  const int b = blockIdx.x;
  const int tid = threadIdx.x;
  // convert conv weights to half2 pairs (all blocks write identical values)
  for (int wi = tid; wi < 343; wi += 256)
    w16[wi] = __floats2half2_rn(cw[wi * 2], cw[wi * 2 + 1]);

  const int r = tid >> 6, c = tid & 63;
  const f32x4* ps4 = (const f32x4*)(psum + ((size_t)b * 64 + c) * NB + r * 128);
  const f32x4* pm4 = (const f32x4*)(pmax + ((size_t)b * 64 + c) * NB + r * 128);
  float s = 0.f, m = -INFINITY;
  #pragma unroll 8
  for (int j = 0; j < 32; ++j) {
    f32x4 vs = ps4[j];
    f32x4 vm = pm4[j];
    s += (vs.x + vs.y) + (vs.z + vs.w);
    m = fmaxf(m, fmaxf(fmaxf(vm.x, vm.y), fmaxf(vm.z, vm.w)));
  }
  __shared__ float ls[4][64];
  __shared__ float lm[4][64];
  ls[r][c] = s; lm[r][c] = m;
  __syncthreads();
  if (tid < 64) {
    const int cc = tid;
    float ss = ls[0][cc] + ls[1][cc] + ls[2][cc] + ls[3][cc];
    float mm = fmaxf(fmaxf(lm[0][cc], lm[1][cc]), fmaxf(lm[2][cc], lm[3][cc]));
    float avg = ss * (1.f / SPATIAL);

    float w1c[4];
    #pragma unroll
    for (int j = 0; j < 4; ++j) w1c[j] = w1[cc * 4 + j];
    float pa[4], pm[4];
    #pragma unroll
    for (int j = 0; j < 4; ++j) { pa[j] = avg * w1c[j]; pm[j] = mm * w1c[j]; }
    #pragma unroll
    for (int mask = 1; mask < 64; mask <<= 1) {
      #pragma unroll
      for (int j = 0; j < 4; ++j) {
        pa[j] += __shfl_xor(pa[j], mask);
        pm[j] += __shfl_xor(pm[j], mask);
      }
    }
    float za = b2[cc], zm = b2[cc];
    #pragma unroll
    for (int j = 0; j < 4; ++j) {
      float ha = fmaxf(pa[j] + b1[j], 0.f);
      float hm = fmaxf(pm[j] + b1[j], 0.f);
      za += ha * w2[j * 64 + cc];
      zm += hm * w2[j * 64 + cc];
    }
    ca[b * 64 + cc] = sigmoidf_(za) + sigmoidf_(zm);
  }
}

// ---------------- Kernel C (fast): per-voxel channel mean/max from x16 -> sp half2 ----------------
__global__ __launch_bounds__(256) void spstats16_kernel(
    const __half* __restrict__ x16, const float* __restrict__ ca, __half2* __restrict__ sp) {
  const int tid = threadIdx.x, lane = tid & 63, w = tid >> 6;
  const int q = lane >> 3, g = lane & 7;      // 8 voxels/wave, 8 ch-groups of 8
  const int waveId = blockIdx.x * 4 + w;
  const int nWaves = gridDim.x * 4;
  const int NGRP = BATCH * SPATIAL / 8;
  const u32x4* x4 = (const u32x4*)x16;
  #pragma unroll 2
  for (int grp = waveId; grp < NGRP; grp += nWaves) {
    int p = grp * 8 + q;
    int b = p >> 18;
    union { u32x4 v; unsigned u[4]; } uu;
    uu.v = x4[(size_t)p * 8 + g];
    const float* cab = ca + b * 64 + g * 8;
    f32x4 c0 = *(const f32x4*)cab;
    f32x4 c1 = *(const f32x4*)(cab + 4);
    float2 f0 = __half22float2(*(__half2*)&uu.u[0]);
    float2 f1 = __half22float2(*(__half2*)&uu.u[1]);
    float2 f2 = __half22float2(*(__half2*)&uu.u[2]);
    float2 f3 = __half22float2(*(__half2*)&uu.u[3]);
    float a0 = f0.x*c0.x, a1 = f0.y*c0.y, a2 = f1.x*c0.z, a3 = f1.y*c0.w;
    float a4 = f2.x*c1.x, a5 = f2.y*c1.y, a6 = f3.x*c1.z, a7 = f3.y*c1.w;
    float s = ((a0+a1)+(a2+a3)) + ((a4+a5)+(a6+a7));
    float m = fmaxf(fmaxf(fmaxf(a0,a1),fmaxf(a2,a3)), fmaxf(fmaxf(a4,a5),fmaxf(a6,a7)));
    #pragma unroll
    for (int mask = 1; mask < 8; mask <<= 1) {
      s += __shfl_xor(s, mask);
      m = fmaxf(m, __shfl_xor(m, mask));
    }
    if (g == 0) sp[p] = __floats2half2_rn(s * (1.f / 64.f), m);
  }
}

// ---------------- Kernel C (fallback): from fp32 x ----------------
__global__ __launch_bounds__(256) void spstats_kernel(
    const float* __restrict__ x, const float* __restrict__ ca, __half2* __restrict__ sp) {
  const int tid = threadIdx.x, lane = tid & 63, w = tid >> 6;
  const int q = lane >> 4, g = lane & 15;
  const int waveId = blockIdx.x * 4 + w;
  const int nWaves = gridDim.x * 4;
  const int NGRP = BATCH * SPATIAL / 4;
  const float4* x4  = (const float4*)x;
  const float4* ca4 = (const float4*)ca;
  for (int grp = waveId; grp < NGRP; grp += nWaves) {
    int p = grp * 4 + q;
    int b = p >> 18;
    float4 v  = x4[(size_t)p * 16 + g];
    float4 cv = ca4[b * 16 + g];
    float ax = v.x * cv.x, ay = v.y * cv.y, az = v.z * cv.z, aw = v.w * cv.w;
    float s = ax + ay + az + aw;
    float m = fmaxf(fmaxf(ax, ay), fmaxf(az, aw));
    #pragma unroll
    for (int mask = 1; mask < 16; mask <<= 1) {
      s += __shfl_xor(s, mask);
      m = fmaxf(m, __shfl_xor(m, mask));
    }
    if (g == 0) sp[p] = __floats2half2_rn(s * (1.f / 64.f), m);
  }
}

// ---------------- Kernel D: LDS-tiled conv (dot2 f32-accum) + wave-private fused stream ----------------
// Round-8 geometry: CZT=8, 1024 blocks; wave ty owns z-pair zb=ty*2, 2y x 2z outputs.
#define CZT 8
#define CYT 2
#define CPL (CZT + 6)     // 14
#define CRW (CYT + 6)     // 8
#define CXW 70
template<bool X16>
__global__ __launch_bounds__(256) void conv_final_kernel(
    const __half2* __restrict__ sp, const __half2* __restrict__ w16,
    const float* __restrict__ x, const __half* __restrict__ x16,
    const float* __restrict__ ca, float* __restrict__ out) {
  __shared__ __half2 tile[CPL * CRW * CXW];   // 31360 B

  const int bid = blockIdx.x;
  const int zg = bid & 7;
  const int yg = (bid >> 3) & 31;
  const int b  = bid >> 8;
  const int z0 = zg * CZT;
  const int y0 = yg * CYT;

  const __half2* spb = sp + (size_t)b * SPATIAL;

  const int NE = CPL * CRW * CXW;   // 7840
  for (int e = threadIdx.x; e < NE; e += 256) {
    int pl  = e / (CRW * CXW);
    int rem = e - pl * (CRW * CXW);
    int row = rem / CXW;
    int xi  = rem - row * CXW;
    int z = z0 + pl - 3;
    int y = y0 + row - 3;
    int xx = xi - 3;
    __half2 v = __floats2half2_rn(0.f, 0.f);
    if ((unsigned)z < 64u && (unsigned)y < 64u && (unsigned)xx < 64u)
      v = spb[(z << 12) + (y << 6) + xx];
    tile[e] = v;
  }
  __syncthreads();

  const int lane = threadIdx.x & 63;   // voxel x this lane convolves
  const int ty   = threadIdx.x >> 6;
  const int zb   = ty * 2;

  float accf[2][2] = {{0.f, 0.f}, {0.f, 0.f}};   // [dz][dy]

  for (int pp = 0; pp < 8; ++pp) {
    const int pl = zb + pp;
    #pragma unroll
    for (int ry = 0; ry < 8; ++ry) {
      const __half2* rowp = tile + (pl * CRW + ry) * CXW + lane;
      __half2 h[7];
      #pragma unroll
      for (int k = 0; k < 7; ++k) h[k] = rowp[k];
      #pragma unroll
      for (int dz = 0; dz < 2; ++dz) {
        const int kz = pp - dz;
        if ((unsigned)kz > 6u) continue;   // wave-uniform branch
        #pragma unroll
        for (int dy = 0; dy < 2; ++dy) {
          const int ky = ry - dy;
          if ((unsigned)ky > 6u) continue; // compile-time (ry unrolled)
          const __half2* wp = w16 + kz * 49 + ky * 7;  // wave-uniform -> scalar loads
          float a = accf[dz][dy];
          #pragma unroll
          for (int kx = 0; kx < 7; ++kx)
            a = dot2acc(h[kx], wp[kx], a);
          accf[dz][dy] = a;
        }
      }
    }
  }

  // ---- wave-private fused stream: sa in registers, per-voxel sa via one __shfl ----
  if (X16) {
    const float4* ca4 = (const float4*)ca;
    const float4 cav = ca4[b * 16 + (lane & 15)];
    const uint2* xr = (const uint2*)x16;
    #pragma unroll
    for (int dz = 0; dz < 2; ++dz) {
      #pragma unroll
      for (int dy = 0; dy < 2; ++dy) {
        const float s_own = sigmoidf_(accf[dz][dy]);
        const int z = z0 + zb + dz;
        const int y = y0 + dy;
        const size_t base = (((size_t)b * 64 + z) * 64 + y) * 1024;
        #pragma unroll 8
        for (int k = 0; k < 16; ++k) {
          const int f = lane + k * 64;
          const float sv = __shfl(s_own, (lane >> 4) + k * 4);
          uint2 u = xr[base + f];
          float2 t0 = __half22float2(*(__half2*)&u.x);
          float2 t1 = __half22float2(*(__half2*)&u.y);
          f32x4 o;
          o.x = t0.x * cav.x * sv; o.y = t0.y * cav.y * sv;
          o.z = t1.x * cav.z * sv; o.w = t1.y * cav.w * sv;
          __builtin_nontemporal_store(o, (f32x4*)out + base + f);
        }
      }
    }
  } else {
    const float4* x4 = (const float4*)x;
    const float4* ca4 = (const float4*)ca;
    const float4 cav = ca4[b * 16 + (lane & 15)];
    #pragma unroll
    for (int dz = 0; dz < 2; ++dz) {
      #pragma unroll
      for (int dy = 0; dy < 2; ++dy) {
        const float s_own = sigmoidf_(accf[dz][dy]);
        const int z = z0 + zb + dz;
        const int y = y0 + dy;
        const size_t base = (((size_t)b * 64 + z) * 64 + y) * 1024;
        #pragma unroll 8
        for (int k = 0; k < 16; ++k) {
          const int f = lane + k * 64;
          const float sv = __shfl(s_own, (lane >> 4) + k * 4);
          float4 v = x4[base + f];
          f32x4 o;
          o.x = v.x * cav.x * sv; o.y = v.y * cav.y * sv;
          o.z = v.z * cav.z * sv; o.w = v.w * cav.w * sv;
          __builtin_nontemporal_store(o, (f32x4*)(out + (base + f) * 4));
        }
      }
    }
  }
}

extern "C" void kernel_launch(void* const* d_in, const int* in_sizes, int n_in,
                              void* d_out, int out_size, void* d_ws, size_t ws_size,
                              hipStream_t stream) {
  const float* x  = (const float*)d_in[0];
  const float* w1 = (const float*)d_in[1];
  const float* b1 = (const float*)d_in[2];
  const float* w2 = (const float*)d_in[3];
  const float* b2 = (const float*)d_in[4];
  const float* cw = (const float*)d_in[5];
  float* out = (float*)d_out;

  const size_t x16_bytes = (size_t)BATCH * SPATIAL * 64 * 2;  // 134 MB
  const size_t sp_bytes  = (size_t)BATCH * SPATIAL * 4;       // 4 MB half2
  const size_t red_bytes = (size_t)BATCH * NB * 64 * 4;       // 512 KB each
  const size_t tail_bytes = 256 * 4 + 344 * 4 + 1024;         // ca + w16 + pad
  const size_t need = x16_bytes + sp_bytes + 2 * red_bytes + tail_bytes;

  const int conv_grid = BATCH * 32 * 8;   // 1024

  if (ws_size >= need) {
    __half*  x16  = (__half*)d_ws;
    __half2* sp   = (__half2*)((char*)d_ws + x16_bytes);
    float*   psum = (float*)((char*)sp + sp_bytes);
    float*   pmax = psum + (size_t)BATCH * NB * 64;
    float*   ca   = pmax + (size_t)BATCH * NB * 64;
    __half2* w16  = (__half2*)(ca + 256);

    pool_partial_kernel<true><<<BATCH * NB, 256, 0, stream>>>(x, x16, psum, pmax);
    ca_kernel<<<BATCH, 256, 0, stream>>>(psum, pmax, w1, b1, w2, b2, cw, w16, ca);
    spstats16_kernel<<<2048, 256, 0, stream>>>(x16, ca, sp);
    conv_final_kernel<true><<<conv_grid, 256, 0, stream>>>(sp, w16, x, x16, ca, out);
  } else {
    __half2* sp   = (__half2*)d_ws;
    float*   psum = (float*)((char*)sp + sp_bytes);
    float*   pmax = psum + (size_t)BATCH * NB * 64;
    float*   ca   = pmax + (size_t)BATCH * NB * 64;
    __half2* w16  = (__half2*)(ca + 256);

    pool_partial_kernel<false><<<BATCH * NB, 256, 0, stream>>>(x, nullptr, psum, pmax);
    ca_kernel<<<BATCH, 256, 0, stream>>>(psum, pmax, w1, b1, w2, b2, cw, w16, ca);
    spstats_kernel<<<2048, 256, 0, stream>>>(x, ca, sp);
    conv_final_kernel<false><<<conv_grid, 256, 0, stream>>>(sp, w16, x, nullptr, ca, out);
  }
}

// Round 11
// 182.748 us; speedup vs baseline: 1.3339x; 1.3339x over previous
//
#include <hip/hip_runtime.h>
#include <hip/hip_fp16.h>
#include <math.h>

#define BATCH 4
#define SPATIAL (64*64*64)   // D*H*W = 262144
#define NB 512               // partial-reduction chunks per batch

typedef float f32x4 __attribute__((ext_vector_type(4)));
typedef unsigned int u32x4 __attribute__((ext_vector_type(4)));

__device__ __forceinline__ float sigmoidf_(float z) { return 1.f / (1.f + expf(-z)); }

// ---------------- Kernel A: partial spatial sum/max per (b, chunk, c); optional fp16 x copy ----------------
// psum/pmax layout: [b][c][chunk] (transposed for contiguous ca_kernel reads)
// NOTE: one contiguous float4/lane/iter (1 KB per wave instruction) — R10 showed that
// splitting this into 2 strided 16B loads costs ~60 us (DRAM burst efficiency).
template<bool W16>
__global__ __launch_bounds__(256) void pool_partial_kernel(
    const float* __restrict__ x, __half* __restrict__ x16,
    float* __restrict__ psum, float* __restrict__ pmax) {
  const int b     = blockIdx.x / NB;
  const int chunk = blockIdx.x % NB;
  const int tid  = threadIdx.x;
  const int w    = tid >> 6;
  const int lane = tid & 63;
  const int q    = lane >> 4;         // position-in-group (0..3)
  const int g    = lane & 15;         // channel group (4 ch each)

  const f32x4* xb = (const f32x4*)x + (size_t)b * SPATIAL * 16;
  uint2* x16b = (uint2*)x16 + (size_t)b * SPATIAL * 16;

  float s0=0.f, s1=0.f, s2=0.f, s3=0.f;
  float m0=-INFINITY, m1=-INFINITY, m2=-INFINITY, m3=-INFINITY;

  const int PPB = SPATIAL / NB;       // 512 positions per block
  #pragma unroll 8
  for (int i = 0; i < PPB / 16; ++i) {
    int p = chunk * PPB + i * 16 + w * 4 + q;
    size_t gi = (size_t)p * 16 + g;
    f32x4 v;
    if (W16) v = __builtin_nontemporal_load(xb + gi);   // don't pollute L3 with fp32 x
    else     v = xb[gi];
    if (W16) {
      union { __half2 h[2]; uint2 u; } pk;
      pk.h[0] = __floats2half2_rn(v.x, v.y);
      pk.h[1] = __floats2half2_rn(v.z, v.w);
      x16b[gi] = pk.u;                                  // normal store: want L3 residency
    }
    s0 += v.x; s1 += v.y; s2 += v.z; s3 += v.w;
    m0 = fmaxf(m0, v.x); m1 = fmaxf(m1, v.y); m2 = fmaxf(m2, v.z); m3 = fmaxf(m3, v.w);
  }
  #pragma unroll
  for (int mask = 16; mask <= 32; mask <<= 1) {
    s0 += __shfl_xor(s0, mask); s1 += __shfl_xor(s1, mask);
    s2 += __shfl_xor(s2, mask); s3 += __shfl_xor(s3, mask);
    m0 = fmaxf(m0, __shfl_xor(m0, mask)); m1 = fmaxf(m1, __shfl_xor(m1, mask));
    m2 = fmaxf(m2, __shfl_xor(m2, mask)); m3 = fmaxf(m3, __shfl_xor(m3, mask));
  }
  __shared__ float lsum[4][64];
  __shared__ float lmax[4][64];
  if (q == 0) {
    lsum[w][g*4+0] = s0; lsum[w][g*4+1] = s1; lsum[w][g*4+2] = s2; lsum[w][g*4+3] = s3;
    lmax[w][g*4+0] = m0; lmax[w][g*4+1] = m1; lmax[w][g*4+2] = m2; lmax[w][g*4+3] = m3;
  }
  __syncthreads();
  if (tid < 64) {
    float s = lsum[0][tid] + lsum[1][tid] + lsum[2][tid] + lsum[3][tid];
    float m = fmaxf(fmaxf(lmax[0][tid], lmax[1][tid]), fmaxf(lmax[2][tid], lmax[3][tid]));
    psum[((size_t)b * 64 + tid) * NB + chunk] = s;   // transposed
    pmax[((size_t)b * 64 + tid) * NB + chunk] = m;
  }
}

// ---------------- Kernel B: finalize pools + MLP -> ca[B][C]; also emit half2 conv weights ----------------
__global__ __launch_bounds__(256) void ca_kernel(
    const float* __restrict__ psum, const float* __restrict__ pmax,
    const float* __restrict__ w1, const float* __restrict__ b1,
    const float* __restrict__ w2, const float* __restrict__ b2,
    const float* __restrict__ cw, __half2* __restrict__ w16,
    float* __restrict__ ca) {
  const int b = blockIdx.x;
  const int tid = threadIdx.x;
  // convert conv weights to half2 pairs (all blocks write identical values)
  for (int wi = tid; wi < 343; wi += 256)
    w16[wi] = __floats2half2_rn(cw[wi * 2], cw[wi * 2 + 1]);

  const int r = tid >> 6, c = tid & 63;
  const f32x4* ps4 = (const f32x4*)(psum + ((size_t)b * 64 + c) * NB + r * 128);
  const f32x4* pm4 = (const f32x4*)(pmax + ((size_t)b * 64 + c) * NB + r * 128);
  float s = 0.f, m = -INFINITY;
  #pragma unroll 8
  for (int j = 0; j < 32; ++j) {
    f32x4 vs = ps4[j];
    f32x4 vm = pm4[j];
    s += (vs.x + vs.y) + (vs.z + vs.w);
    m = fmaxf(m, fmaxf(fmaxf(vm.x, vm.y), fmaxf(vm.z, vm.w)));
  }
  __shared__ float ls[4][64];
  __shared__ float lm[4][64];
  ls[r][c] = s; lm[r][c] = m;
  __syncthreads();
  if (tid < 64) {
    const int cc = tid;
    float ss = ls[0][cc] + ls[1][cc] + ls[2][cc] + ls[3][cc];
    float mm = fmaxf(fmaxf(lm[0][cc], lm[1][cc]), fmaxf(lm[2][cc], lm[3][cc]));
    float avg = ss * (1.f / SPATIAL);

    float w1c[4];
    #pragma unroll
    for (int j = 0; j < 4; ++j) w1c[j] = w1[cc * 4 + j];
    float pa[4], pm[4];
    #pragma unroll
    for (int j = 0; j < 4; ++j) { pa[j] = avg * w1c[j]; pm[j] = mm * w1c[j]; }
    #pragma unroll
    for (int mask = 1; mask < 64; mask <<= 1) {
      #pragma unroll
      for (int j = 0; j < 4; ++j) {
        pa[j] += __shfl_xor(pa[j], mask);
        pm[j] += __shfl_xor(pm[j], mask);
      }
    }
    float za = b2[cc], zm = b2[cc];
    #pragma unroll
    for (int j = 0; j < 4; ++j) {
      float ha = fmaxf(pa[j] + b1[j], 0.f);
      float hm = fmaxf(pm[j] + b1[j], 0.f);
      za += ha * w2[j * 64 + cc];
      zm += hm * w2[j * 64 + cc];
    }
    ca[b * 64 + cc] = sigmoidf_(za) + sigmoidf_(zm);
  }
}

// ---------------- Kernel C (fast): per-voxel channel mean/max from x16 -> sp half2 ----------------
__global__ __launch_bounds__(256) void spstats16_kernel(
    const __half* __restrict__ x16, const float* __restrict__ ca, __half2* __restrict__ sp) {
  const int tid = threadIdx.x, lane = tid & 63, w = tid >> 6;
  const int q = lane >> 3, g = lane & 7;      // 8 voxels/wave, 8 ch-groups of 8
  const int waveId = blockIdx.x * 4 + w;
  const int nWaves = gridDim.x * 4;
  const int NGRP = BATCH * SPATIAL / 8;
  const u32x4* x4 = (const u32x4*)x16;
  #pragma unroll 2
  for (int grp = waveId; grp < NGRP; grp += nWaves) {
    int p = grp * 8 + q;
    int b = p >> 18;
    union { u32x4 v; unsigned u[4]; } uu;
    uu.v = x4[(size_t)p * 8 + g];
    const float* cab = ca + b * 64 + g * 8;
    f32x4 c0 = *(const f32x4*)cab;
    f32x4 c1 = *(const f32x4*)(cab + 4);
    float2 f0 = __half22float2(*(__half2*)&uu.u[0]);
    float2 f1 = __half22float2(*(__half2*)&uu.u[1]);
    float2 f2 = __half22float2(*(__half2*)&uu.u[2]);
    float2 f3 = __half22float2(*(__half2*)&uu.u[3]);
    float a0 = f0.x*c0.x, a1 = f0.y*c0.y, a2 = f1.x*c0.z, a3 = f1.y*c0.w;
    float a4 = f2.x*c1.x, a5 = f2.y*c1.y, a6 = f3.x*c1.z, a7 = f3.y*c1.w;
    float s = ((a0+a1)+(a2+a3)) + ((a4+a5)+(a6+a7));
    float m = fmaxf(fmaxf(fmaxf(a0,a1),fmaxf(a2,a3)), fmaxf(fmaxf(a4,a5),fmaxf(a6,a7)));
    #pragma unroll
    for (int mask = 1; mask < 8; mask <<= 1) {
      s += __shfl_xor(s, mask);
      m = fmaxf(m, __shfl_xor(m, mask));
    }
    if (g == 0) sp[p] = __floats2half2_rn(s * (1.f / 64.f), m);
  }
}

// ---------------- Kernel C (fallback): from fp32 x ----------------
__global__ __launch_bounds__(256) void spstats_kernel(
    const float* __restrict__ x, const float* __restrict__ ca, __half2* __restrict__ sp) {
  const int tid = threadIdx.x, lane = tid & 63, w = tid >> 6;
  const int q = lane >> 4, g = lane & 15;
  const int waveId = blockIdx.x * 4 + w;
  const int nWaves = gridDim.x * 4;
  const int NGRP = BATCH * SPATIAL / 4;
  const float4* x4  = (const float4*)x;
  const float4* ca4 = (const float4*)ca;
  for (int grp = waveId; grp < NGRP; grp += nWaves) {
    int p = grp * 4 + q;
    int b = p >> 18;
    float4 v  = x4[(size_t)p * 16 + g];
    float4 cv = ca4[b * 16 + g];
    float ax = v.x * cv.x, ay = v.y * cv.y, az = v.z * cv.z, aw = v.w * cv.w;
    float s = ax + ay + az + aw;
    float m = fmaxf(fmaxf(ax, ay), fmaxf(az, aw));
    #pragma unroll
    for (int mask = 1; mask < 16; mask <<= 1) {
      s += __shfl_xor(s, mask);
      m = fmaxf(m, __shfl_xor(m, mask));
    }
    if (g == 0) sp[p] = __floats2half2_rn(s * (1.f / 64.f), m);
  }
}

// ---------------- Kernel D: LDS-tiled conv (packed half2 math) + wave-private fused stream ----------------
// Tile: x = 0..63 (lanes), CYT=2 y's, CZT=8 z's per block; wave ty owns z-pair zb=ty*2.
// Conv uses v_pk_fma_f16: half2 lanes carry (avg,max) channels; weights pre-paired in w16.
// fp16 accumulators flushed to fp32 once per z-plane (64-term partials) for accuracy.
#define CZT 8
#define CYT 2
#define CPL (CZT + 6)     // 14
#define CRW (CYT + 6)     // 8
#define CXW 70
template<bool X16>
__global__ __launch_bounds__(256) void conv_final_kernel(
    const __half2* __restrict__ sp, const __half2* __restrict__ w16,
    const float* __restrict__ x, const __half* __restrict__ x16,
    const float* __restrict__ ca, float* __restrict__ out) {
  __shared__ __half2 tile[CPL * CRW * CXW];   // 31360 B

  const int bid = blockIdx.x;
  const int zg = bid & 7;
  const int yg = (bid >> 3) & 31;
  const int b  = bid >> 8;
  const int z0 = zg * CZT;
  const int y0 = yg * CYT;

  const __half2* spb = sp + (size_t)b * SPATIAL;

  const int NE = CPL * CRW * CXW;   // 7840
  for (int e = threadIdx.x; e < NE; e += 256) {
    int pl  = e / (CRW * CXW);
    int rem = e - pl * (CRW * CXW);
    int row = rem / CXW;
    int xi  = rem - row * CXW;
    int z = z0 + pl - 3;
    int y = y0 + row - 3;
    int xx = xi - 3;
    __half2 v = __floats2half2_rn(0.f, 0.f);
    if ((unsigned)z < 64u && (unsigned)y < 64u && (unsigned)xx < 64u)
      v = spb[(z << 12) + (y << 6) + xx];
    tile[e] = v;
  }
  __syncthreads();

  const int lane = threadIdx.x & 63;   // voxel x this lane convolves
  const int ty   = threadIdx.x >> 6;
  const int zb   = ty * 2;

  float accf[2][2] = {{0.f, 0.f}, {0.f, 0.f}};   // [dz][dy]

  const __half2 zero2 = __floats2half2_rn(0.f, 0.f);
  for (int pp = 0; pp < 8; ++pp) {
    const int pl = zb + pp;
    __half2 a00 = zero2, a01 = zero2, a10 = zero2, a11 = zero2;
    #pragma unroll
    for (int ry = 0; ry < 8; ++ry) {
      const __half2* rowp = tile + (pl * CRW + ry) * CXW + lane;
      __half2 h[7];
      #pragma unroll
      for (int k = 0; k < 7; ++k) h[k] = rowp[k];
      #pragma unroll
      for (int dz = 0; dz < 2; ++dz) {
        const int kz = pp - dz;
        if ((unsigned)kz > 6u) continue;   // wave-uniform branch
        #pragma unroll
        for (int dy = 0; dy < 2; ++dy) {
          const int ky = ry - dy;
          if ((unsigned)ky > 6u) continue; // compile-time (ry unrolled)
          const __half2* wp = w16 + kz * 49 + ky * 7;  // wave-uniform -> scalar loads
          __half2 a = (dz == 0) ? (dy == 0 ? a00 : a01) : (dy == 0 ? a10 : a11);
          #pragma unroll
          for (int kx = 0; kx < 7; ++kx)
            a = __hfma2(h[kx], wp[kx], a);
          if (dz == 0) { if (dy == 0) a00 = a; else a01 = a; }
          else         { if (dy == 0) a10 = a; else a11 = a; }
        }
      }
    }
    accf[0][0] += __low2float(a00) + __high2float(a00);
    accf[0][1] += __low2float(a01) + __high2float(a01);
    accf[1][0] += __low2float(a10) + __high2float(a10);
    accf[1][1] += __low2float(a11) + __high2float(a11);
  }

  // ---- wave-private fused stream: sa in registers, per-voxel sa via one __shfl ----
  if (X16) {
    const float4* ca4 = (const float4*)ca;
    const float4 cav = ca4[b * 16 + (lane & 15)];
    const uint2* xr = (const uint2*)x16;
    #pragma unroll
    for (int dz = 0; dz < 2; ++dz) {
      #pragma unroll
      for (int dy = 0; dy < 2; ++dy) {
        const float s_own = sigmoidf_(accf[dz][dy]);
        const int z = z0 + zb + dz;
        const int y = y0 + dy;
        const size_t base = (((size_t)b * 64 + z) * 64 + y) * 1024;
        #pragma unroll 8
        for (int k = 0; k < 16; ++k) {
          const int f = lane + k * 64;
          const float sv = __shfl(s_own, (lane >> 4) + k * 4);
          uint2 u = xr[base + f];
          float2 t0 = __half22float2(*(__half2*)&u.x);
          float2 t1 = __half22float2(*(__half2*)&u.y);
          f32x4 o;
          o.x = t0.x * cav.x * sv; o.y = t0.y * cav.y * sv;
          o.z = t1.x * cav.z * sv; o.w = t1.y * cav.w * sv;
          __builtin_nontemporal_store(o, (f32x4*)out + base + f);
        }
      }
    }
  } else {
    const float4* x4 = (const float4*)x;
    const float4* ca4 = (const float4*)ca;
    const float4 cav = ca4[b * 16 + (lane & 15)];
    #pragma unroll
    for (int dz = 0; dz < 2; ++dz) {
      #pragma unroll
      for (int dy = 0; dy < 2; ++dy) {
        const float s_own = sigmoidf_(accf[dz][dy]);
        const int z = z0 + zb + dz;
        const int y = y0 + dy;
        const size_t base = (((size_t)b * 64 + z) * 64 + y) * 1024;
        #pragma unroll 8
        for (int k = 0; k < 16; ++k) {
          const int f = lane + k * 64;
          const float sv = __shfl(s_own, (lane >> 4) + k * 4);
          float4 v = x4[base + f];
          f32x4 o;
          o.x = v.x * cav.x * sv; o.y = v.y * cav.y * sv;
          o.z = v.z * cav.z * sv; o.w = v.w * cav.w * sv;
          __builtin_nontemporal_store(o, (f32x4*)(out + (base + f) * 4));
        }
      }
    }
  }
}

extern "C" void kernel_launch(void* const* d_in, const int* in_sizes, int n_in,
                              void* d_out, int out_size, void* d_ws, size_t ws_size,
                              hipStream_t stream) {
  const float* x  = (const float*)d_in[0];
  const float* w1 = (const float*)d_in[1];
  const float* b1 = (const float*)d_in[2];
  const float* w2 = (const float*)d_in[3];
  const float* b2 = (const float*)d_in[4];
  const float* cw = (const float*)d_in[5];
  float* out = (float*)d_out;

  const size_t x16_bytes = (size_t)BATCH * SPATIAL * 64 * 2;  // 134 MB
  const size_t sp_bytes  = (size_t)BATCH * SPATIAL * 4;       // 4 MB half2
  const size_t red_bytes = (size_t)BATCH * NB * 64 * 4;       // 512 KB each
  const size_t tail_bytes = 256 * 4 + 344 * 4 + 1024;         // ca + w16 + pad
  const size_t need = x16_bytes + sp_bytes + 2 * red_bytes + tail_bytes;

  if (ws_size >= need) {
    __half*  x16  = (__half*)d_ws;
    __half2* sp   = (__half2*)((char*)d_ws + x16_bytes);
    float*   psum = (float*)((char*)sp + sp_bytes);
    float*   pmax = psum + (size_t)BATCH * NB * 64;
    float*   ca   = pmax + (size_t)BATCH * NB * 64;
    __half2* w16  = (__half2*)(ca + 256);

    pool_partial_kernel<true><<<BATCH * NB, 256, 0, stream>>>(x, x16, psum, pmax);
    ca_kernel<<<BATCH, 256, 0, stream>>>(psum, pmax, w1, b1, w2, b2, cw, w16, ca);
    spstats16_kernel<<<2048, 256, 0, stream>>>(x16, ca, sp);
    conv_final_kernel<true><<<BATCH * 32 * 8, 256, 0, stream>>>(sp, w16, x, x16, ca, out);
  } else {
    __half2* sp   = (__half2*)d_ws;
    float*   psum = (float*)((char*)sp + sp_bytes);
    float*   pmax = psum + (size_t)BATCH * NB * 64;
    float*   ca   = pmax + (size_t)BATCH * NB * 64;
    __half2* w16  = (__half2*)(ca + 256);

    pool_partial_kernel<false><<<BATCH * NB, 256, 0, stream>>>(x, nullptr, psum, pmax);
    ca_kernel<<<BATCH, 256, 0, stream>>>(psum, pmax, w1, b1, w2, b2, cw, w16, ca);
    spstats_kernel<<<2048, 256, 0, stream>>>(x, ca, sp);
    conv_final_kernel<false><<<BATCH * 32 * 8, 256, 0, stream>>>(sp, w16, x, nullptr, ca, out);
  }
}